// Round 9
// baseline (595.258 us; speedup 1.0000x reference)
//
#include <hip/hip_runtime.h>
#include <math.h>

// Sizes (fixed for this problem)
#define B    256
#define T    512
#define CTX  512
#define MEL  160
#define PRE  128
#define ATT  256
#define RNN  768
#define G3   2304   // 3*RNN

typedef __attribute__((ext_vector_type(8))) short short8;
typedef __attribute__((ext_vector_type(4))) float f32x4;

__device__ __forceinline__ unsigned short f2bf(float f) {
    unsigned u = __float_as_uint(f);
    unsigned r = (u + 0x7fffu + ((u >> 16) & 1u)) >> 16;
    return (unsigned short)r;
}
__device__ __forceinline__ float bf2f(unsigned short h) {
    return __uint_as_float((unsigned)h << 16);
}

__device__ __forceinline__ void conv8(const float* p, short8* hi8, short8* lo8) {
    const float4 v0 = *(const float4*)p;
    const float4 v1 = *(const float4*)(p + 4);
    const float av[8] = {v0.x, v0.y, v0.z, v0.w, v1.x, v1.y, v1.z, v1.w};
    short hi[8], lo[8];
    #pragma unroll
    for (int u = 0; u < 8; ++u) {
        const unsigned short h = f2bf(av[u]);
        hi[u] = (short)h;
        lo[u] = (short)f2bf(av[u] - bf2f(h));
    }
    *hi8 = *(const short8*)hi;
    *lo8 = *(const short8*)lo;
}

// ---------------------------------------------------------------------------
// 64x64 bf16-MFMA split-precision GEMM tile body (verified R5-R8).
// ---------------------------------------------------------------------------
__device__ __forceinline__ void gemm64_body(
        const float* __restrict__ A, const float* __restrict__ W,
        float* __restrict__ C, int m0, int n0, int tid,
        short* AH, short* AL, short* WH, short* WL) {
    const int lane = tid & 63;
    const int wave = tid >> 6;
    const int wm = wave >> 1, wn = wave & 1;

    f32x4 acc[2][2] = {{{0.f, 0.f, 0.f, 0.f}, {0.f, 0.f, 0.f, 0.f}},
                       {{0.f, 0.f, 0.f, 0.f}, {0.f, 0.f, 0.f, 0.f}}};

    for (int k0 = 0; k0 < RNN; k0 += 64) {
        #pragma unroll
        for (int si = 0; si < 2; ++si) {
            const int s = tid + si * 256;
            const int sub = s >> 6;
            const int ln = s & 63;
            const int row = (sub >> 1) * 16 + (ln & 15);
            const int kk = (sub & 1) * 32 + (ln >> 4) * 8;
            conv8(A + (size_t)(m0 + row) * RNN + k0 + kk,
                  (short8*)&AH[s * 8], (short8*)&AL[s * 8]);
            conv8(W + (size_t)(n0 + row) * RNN + k0 + kk,
                  (short8*)&WH[s * 8], (short8*)&WL[s * 8]);
        }
        __syncthreads();

        #pragma unroll
        for (int ks = 0; ks < 2; ++ks) {
            short8 ah[2], al[2], wh[2], wl[2];
            #pragma unroll
            for (int i = 0; i < 2; ++i) {
                const int asub = ((wm * 2 + i) * 2 + ks);
                ah[i] = *(const short8*)&AH[(asub * 64 + lane) * 8];
                al[i] = *(const short8*)&AL[(asub * 64 + lane) * 8];
                const int wsub = ((wn * 2 + i) * 2 + ks);
                wh[i] = *(const short8*)&WH[(wsub * 64 + lane) * 8];
                wl[i] = *(const short8*)&WL[(wsub * 64 + lane) * 8];
            }
            #pragma unroll
            for (int i = 0; i < 2; ++i)
                #pragma unroll
                for (int j = 0; j < 2; ++j) {
                    acc[i][j] = __builtin_amdgcn_mfma_f32_16x16x32_bf16(ah[i], wh[j], acc[i][j], 0, 0, 0);
                    acc[i][j] = __builtin_amdgcn_mfma_f32_16x16x32_bf16(al[i], wh[j], acc[i][j], 0, 0, 0);
                    acc[i][j] = __builtin_amdgcn_mfma_f32_16x16x32_bf16(ah[i], wl[j], acc[i][j], 0, 0, 0);
                }
        }
        __syncthreads();
    }

    const int rowq = lane >> 4, col = lane & 15;
    #pragma unroll
    for (int i = 0; i < 2; ++i)
        #pragma unroll
        for (int j = 0; j < 2; ++j) {
            const int rbase = m0 + wm * 32 + i * 16 + rowq * 4;
            const int cidx = n0 + wn * 32 + j * 16 + col;
            #pragma unroll
            for (int r = 0; r < 4; ++r)
                C[(size_t)(rbase + r) * G3 + cidx] = acc[i][j][r];
        }
}

// ---------------------------------------------------------------------------
// prep: blocks [0,226) wconv (fragment-order hi/lo); block 0 also zeroes
// rowcnt. blocks [226,370): gh0 = h_dec0 @ dec0_wh^T; [370,514): gh1.
// ---------------------------------------------------------------------------
__global__ __launch_bounds__(256) void prep_kernel(
        const float* __restrict__ pw1, const float* __restrict__ pw2,
        const float* __restrict__ wi, const float* __restrict__ wh,
        const float* __restrict__ qw,
        short* __restrict__ p1h, short* __restrict__ p1l,
        short* __restrict__ p2h, short* __restrict__ p2l,
        short* __restrict__ wih, short* __restrict__ wil,
        short* __restrict__ whh, short* __restrict__ whl,
        short* __restrict__ qwh, short* __restrict__ qwl,
        const float* __restrict__ h_dec0, const float* __restrict__ dec0_wh,
        const float* __restrict__ h_dec1, const float* __restrict__ dec1_wh,
        float* __restrict__ gh0, float* __restrict__ gh1,
        unsigned* __restrict__ rowcnt) {
    __shared__ __align__(16) short AH[4096];
    __shared__ __align__(16) short AL[4096];
    __shared__ __align__(16) short WH[4096];
    __shared__ __align__(16) short WL[4096];
    const int blk = blockIdx.x;
    const int tid = threadIdx.x;

    if (blk < 226) {
        if (blk == 0) rowcnt[tid] = 0;   // reset per call (replay-safe)
        int s = blk * 256 + tid;
        const float* src; short *dh, *dl; int K, KS, slot;
        if (s < 2560)                  { src = pw1; dh = p1h; dl = p1l; K = MEL; KS = 5; slot = s; }
        else if ((s -= 2560) < 2048)   { src = pw2; dh = p2h; dl = p2l; K = PRE; KS = 4; slot = s; }
        else if ((s -= 2048) < 12288)  { src = wi;  dh = wih; dl = wil; K = PRE; KS = 4; slot = s; }
        else if ((s -= 12288) < 24576) { src = wh;  dh = whh; dl = whl; K = ATT; KS = 8; slot = s; }
        else if ((s -= 24576) < 16384) { src = qw;  dh = qwh; dl = qwl; K = ATT; KS = 8; slot = s; }
        else return;
        const int lane = slot & 63;
        const int ks = (slot >> 6) % KS;
        const int nt = (slot >> 6) / KS;
        const int n = nt * 16 + (lane & 15);
        const int k = ks * 32 + (lane >> 4) * 8;
        conv8(src + (size_t)n * K + k,
              (short8*)(dh + (size_t)slot * 8), (short8*)(dl + (size_t)slot * 8));
        return;
    }
    const int u = blk - 226;
    const float* A; const float* W; float* C;
    int r;
    if (u < 144) { A = h_dec0; W = dec0_wh; C = gh0; r = u; }
    else         { A = h_dec1; W = dec1_wh; C = gh1; r = u - 144; }
    gemm64_body(A, W, C, (r / 36) * 64, (r % 36) * 64, tid, AH, AL, WH, WL);
}

// ---------------------------------------------------------------------------
// front_mfma: PreNet -> attention GRU -> q projection (R7-verbatim)
// grid: 16 blocks x 512 threads
// ---------------------------------------------------------------------------
__global__ __launch_bounds__(512) void front_mfma_kernel(
        const float* __restrict__ x, const float* __restrict__ b1,
        const float* __restrict__ b2, const float* __restrict__ h_att,
        const float* __restrict__ bi, const float* __restrict__ bh,
        const float* __restrict__ qb,
        const short* __restrict__ p1h, const short* __restrict__ p1l,
        const short* __restrict__ p2h, const short* __restrict__ p2l,
        const short* __restrict__ wih, const short* __restrict__ wil,
        const short* __restrict__ whh, const short* __restrict__ whl,
        const short* __restrict__ qwh, const short* __restrict__ qwl,
        float* __restrict__ h_att_out, float* __restrict__ x_dec,
        float* __restrict__ q) {
    __shared__ __align__(16) short AH[8][64][8];
    __shared__ __align__(16) short AL[8][64][8];
    __shared__ __align__(16) float S[16][RNN];
    __shared__ __align__(16) float S2[16][RNN];
    __shared__ __align__(16) float hs[16][ATT];

    const int tid = threadIdx.x;
    const int wave = tid >> 6, lane = tid & 63;
    const int mb = blockIdx.x * 16;
    const int col = lane & 15, rowq = lane >> 4;

    for (int i = tid; i < 16 * ATT; i += 512)
        hs[i >> 8][i & 255] = h_att[(size_t)(mb + (i >> 8)) * ATT + (i & 255)];
    if (tid < 320) {
        const int sub = tid >> 6, ln = tid & 63;
        const int row = ln & 15, kk = sub * 32 + (ln >> 4) * 8;
        conv8(x + (size_t)(mb + row) * MEL + kk, (short8*)AH[sub][ln], (short8*)AL[sub][ln]);
    }
    __syncthreads();

    {   // prenet layer 1: K=160 (KS=5)
        const int nt = wave;
        f32x4 acc = {0.f, 0.f, 0.f, 0.f};
        #pragma unroll
        for (int ks = 0; ks < 5; ++ks) {
            const short8 a_h = *(const short8*)AH[ks][lane];
            const short8 a_l = *(const short8*)AL[ks][lane];
            const size_t fo = ((size_t)(nt * 5 + ks) * 64 + lane) * 8;
            const short8 b_h = *(const short8*)(p1h + fo);
            const short8 b_l = *(const short8*)(p1l + fo);
            acc = __builtin_amdgcn_mfma_f32_16x16x32_bf16(a_h, b_h, acc, 0, 0, 0);
            acc = __builtin_amdgcn_mfma_f32_16x16x32_bf16(a_l, b_h, acc, 0, 0, 0);
            acc = __builtin_amdgcn_mfma_f32_16x16x32_bf16(a_h, b_l, acc, 0, 0, 0);
        }
        const int j = nt * 16 + col;
        const float bb = b1[j];
        #pragma unroll
        for (int r = 0; r < 4; ++r)
            S[rowq * 4 + r][j] = fmaxf(acc[r] + bb, 0.f);
    }
    __syncthreads();
    if (tid < 256) {
        const int sub = tid >> 6, ln = tid & 63;
        const int row = ln & 15, kk = sub * 32 + (ln >> 4) * 8;
        conv8(&S[row][kk], (short8*)AH[sub][ln], (short8*)AL[sub][ln]);
    }
    __syncthreads();

    {   // prenet layer 2: K=128 (KS=4)
        const int nt = wave;
        f32x4 acc = {0.f, 0.f, 0.f, 0.f};
        #pragma unroll
        for (int ks = 0; ks < 4; ++ks) {
            const short8 a_h = *(const short8*)AH[ks][lane];
            const short8 a_l = *(const short8*)AL[ks][lane];
            const size_t fo = ((size_t)(nt * 4 + ks) * 64 + lane) * 8;
            const short8 b_h = *(const short8*)(p2h + fo);
            const short8 b_l = *(const short8*)(p2l + fo);
            acc = __builtin_amdgcn_mfma_f32_16x16x32_bf16(a_h, b_h, acc, 0, 0, 0);
            acc = __builtin_amdgcn_mfma_f32_16x16x32_bf16(a_l, b_h, acc, 0, 0, 0);
            acc = __builtin_amdgcn_mfma_f32_16x16x32_bf16(a_h, b_l, acc, 0, 0, 0);
        }
        const int j = wave * 16 + col;
        const float bb = b2[j];
        #pragma unroll
        for (int r = 0; r < 4; ++r)
            S[rowq * 4 + r][j] = fmaxf(acc[r] + bb, 0.f);
    }
    __syncthreads();
    if (tid < 256) {
        const int sub = tid >> 6, ln = tid & 63;
        const int row = ln & 15, kk = sub * 32 + (ln >> 4) * 8;
        conv8(&S[row][kk], (short8*)AH[sub][ln], (short8*)AL[sub][ln]);
    }
    __syncthreads();

    // gi = h_pre @ wi^T : 48 ntiles, K=128
    for (int t = 0; t < 6; ++t) {
        const int nt = wave * 6 + t;
        f32x4 acc = {0.f, 0.f, 0.f, 0.f};
        #pragma unroll
        for (int ks = 0; ks < 4; ++ks) {
            const short8 a_h = *(const short8*)AH[ks][lane];
            const short8 a_l = *(const short8*)AL[ks][lane];
            const size_t fo = ((size_t)(nt * 4 + ks) * 64 + lane) * 8;
            const short8 b_h = *(const short8*)(wih + fo);
            const short8 b_l = *(const short8*)(wil + fo);
            acc = __builtin_amdgcn_mfma_f32_16x16x32_bf16(a_h, b_h, acc, 0, 0, 0);
            acc = __builtin_amdgcn_mfma_f32_16x16x32_bf16(a_l, b_h, acc, 0, 0, 0);
            acc = __builtin_amdgcn_mfma_f32_16x16x32_bf16(a_h, b_l, acc, 0, 0, 0);
        }
        const int j = nt * 16 + col;
        #pragma unroll
        for (int r = 0; r < 4; ++r) S[rowq * 4 + r][j] = acc[r];
    }
    __syncthreads();
    {   // conv h_att (K=256)
        const int sub = tid >> 6, ln = tid & 63;
        const int row = ln & 15, kk = sub * 32 + (ln >> 4) * 8;
        conv8(&hs[row][kk], (short8*)AH[sub][ln], (short8*)AL[sub][ln]);
    }
    __syncthreads();

    // gh = h_att @ wh^T : K=256
    for (int t = 0; t < 6; ++t) {
        const int nt = wave * 6 + t;
        f32x4 acc = {0.f, 0.f, 0.f, 0.f};
        #pragma unroll
        for (int ks = 0; ks < 8; ++ks) {
            const short8 a_h = *(const short8*)AH[ks][lane];
            const short8 a_l = *(const short8*)AL[ks][lane];
            const size_t fo = ((size_t)(nt * 8 + ks) * 64 + lane) * 8;
            const short8 b_h = *(const short8*)(whh + fo);
            const short8 b_l = *(const short8*)(whl + fo);
            acc = __builtin_amdgcn_mfma_f32_16x16x32_bf16(a_h, b_h, acc, 0, 0, 0);
            acc = __builtin_amdgcn_mfma_f32_16x16x32_bf16(a_l, b_h, acc, 0, 0, 0);
            acc = __builtin_amdgcn_mfma_f32_16x16x32_bf16(a_h, b_l, acc, 0, 0, 0);
        }
        const int j = nt * 16 + col;
        #pragma unroll
        for (int r = 0; r < 4; ++r) S2[rowq * 4 + r][j] = acc[r];
    }
    __syncthreads();

    // gate math -> h_att_new
    for (int e = tid; e < 16 * ATT; e += 512) {
        const int b = e >> 8, j = e & 255;
        const float ir = S[b][j] + bi[j];
        const float iz = S[b][ATT + j] + bi[ATT + j];
        const float in_ = S[b][2 * ATT + j] + bi[2 * ATT + j];
        const float hr = S2[b][j] + bh[j];
        const float hz = S2[b][ATT + j] + bh[ATT + j];
        const float hn = S2[b][2 * ATT + j] + bh[2 * ATT + j];
        const float r = 1.f / (1.f + expf(-(ir + hr)));
        const float z = 1.f / (1.f + expf(-(iz + hz)));
        const float n = tanhf(in_ + r * hn);
        const float hnew = (1.f - z) * n + z * hs[b][j];
        h_att_out[(size_t)(mb + b) * ATT + j] = hnew;
        x_dec[(size_t)(mb + b) * RNN + j] = hnew;
        hs[b][j] = hnew;
    }
    __syncthreads();
    {   // conv h_att_new (K=256)
        const int sub = tid >> 6, ln = tid & 63;
        const int row = ln & 15, kk = sub * 32 + (ln >> 4) * 8;
        conv8(&hs[row][kk], (short8*)AH[sub][ln], (short8*)AL[sub][ln]);
    }
    __syncthreads();

    // q projection: K=256
    for (int t = 0; t < 4; ++t) {
        const int nt = wave * 4 + t;
        f32x4 acc = {0.f, 0.f, 0.f, 0.f};
        #pragma unroll
        for (int ks = 0; ks < 8; ++ks) {
            const short8 a_h = *(const short8*)AH[ks][lane];
            const short8 a_l = *(const short8*)AL[ks][lane];
            const size_t fo = ((size_t)(nt * 8 + ks) * 64 + lane) * 8;
            const short8 b_h = *(const short8*)(qwh + fo);
            const short8 b_l = *(const short8*)(qwl + fo);
            acc = __builtin_amdgcn_mfma_f32_16x16x32_bf16(a_h, b_h, acc, 0, 0, 0);
            acc = __builtin_amdgcn_mfma_f32_16x16x32_bf16(a_l, b_h, acc, 0, 0, 0);
            acc = __builtin_amdgcn_mfma_f32_16x16x32_bf16(a_h, b_l, acc, 0, 0, 0);
        }
        const int j = nt * 16 + col;
        const float bb = qb[j];
        #pragma unroll
        for (int r = 0; r < 4; ++r)
            q[(size_t)(mb + rowq * 4 + r) * CTX + j] = acc[r] + bb;
    }
}

// ---------------------------------------------------------------------------
// mempass+mid: R7's high-occupancy memory pass (dim3(8,B) = 2048 blocks,
// 32 waves/CU) with "last block per row" mid fused in. The 8th block to
// finish row b (device-scope fetch_add, release/acquire via __threadfence —
// mechanism validated by R6's barrier) performs the ctx reduce -> x_dec and
// softmax*prior -> w_new for that row.
// ---------------------------------------------------------------------------
__global__ void mempass_mid_kernel(const float* __restrict__ mem, const float* __restrict__ w,
                                   const float* __restrict__ q, float* __restrict__ e,
                                   float* __restrict__ ctx_part, float* __restrict__ x_dec,
                                   float* __restrict__ w_new, unsigned* __restrict__ rowcnt) {
    const int b = blockIdx.y, slice = blockIdx.x;
    const int tid = threadIdx.x;
    const int wave = tid >> 6, lane = tid & 63;
    __shared__ float qs[CTX];
    __shared__ float ctx_s[4][CTX];
    __shared__ float red[4];
    __shared__ int last_s;
    for (int i = tid; i < CTX; i += 256) qs[i] = q[(size_t)b * CTX + i];
    __syncthreads();

    const int c0 = lane * 4;
    const int c1 = 256 + lane * 4;
    const float q0 = qs[c0], q1 = qs[c0 + 1], q2 = qs[c0 + 2], q3 = qs[c0 + 3];
    const float q4 = qs[c1], q5 = qs[c1 + 1], q6 = qs[c1 + 2], q7 = qs[c1 + 3];

    const float* mb = mem + (size_t)b * T * CTX;
    float acc[8] = {0.f, 0.f, 0.f, 0.f, 0.f, 0.f, 0.f, 0.f};
    const float invs = 0.04419417382415922f;  // 1/sqrt(512)
    const int t0 = slice * 64 + wave * 16;

    #pragma unroll 4
    for (int i = 0; i < 16; ++i) {
        const int t = t0 + i;
        const float* row = mb + (size_t)t * CTX;
        const float4 m0 = *(const float4*)(row + c0);
        const float4 m1 = *(const float4*)(row + c1);
        const float wt = w[(size_t)b * T + t];
        float ep = m0.x * q0 + m0.y * q1 + m0.z * q2 + m0.w * q3
                 + m1.x * q4 + m1.y * q5 + m1.z * q6 + m1.w * q7;
        #pragma unroll
        for (int off = 32; off; off >>= 1) ep += __shfl_xor(ep, off);
        if (lane == 0) e[(size_t)b * T + t] = ep * invs;
        acc[0] += wt * m0.x; acc[1] += wt * m0.y; acc[2] += wt * m0.z; acc[3] += wt * m0.w;
        acc[4] += wt * m1.x; acc[5] += wt * m1.y; acc[6] += wt * m1.z; acc[7] += wt * m1.w;
    }
    ctx_s[wave][c0] = acc[0]; ctx_s[wave][c0 + 1] = acc[1]; ctx_s[wave][c0 + 2] = acc[2]; ctx_s[wave][c0 + 3] = acc[3];
    ctx_s[wave][c1] = acc[4]; ctx_s[wave][c1 + 1] = acc[5]; ctx_s[wave][c1 + 2] = acc[6]; ctx_s[wave][c1 + 3] = acc[7];
    __syncthreads();
    for (int c = tid; c < CTX; c += 256) {
        const float s = ctx_s[0][c] + ctx_s[1][c] + ctx_s[2][c] + ctx_s[3][c];
        ctx_part[((size_t)slice * B + b) * CTX + c] = s;
    }

    // publish writes, elect last block for this row
    __threadfence();
    __syncthreads();
    if (tid == 0) {
        const unsigned prev = __hip_atomic_fetch_add(&rowcnt[b], 1u,
                                  __ATOMIC_ACQ_REL, __HIP_MEMORY_SCOPE_AGENT);
        last_s = (prev == 7u) ? 1 : 0;
    }
    __syncthreads();
    if (!last_s) return;
    __threadfence();   // acquire side: see the other 7 blocks' ctxp/e writes

    // ---- mid for row b ----
    for (int c = tid; c < CTX; c += 256) {
        float s = 0.f;
        #pragma unroll
        for (int sl = 0; sl < 8; ++sl) s += ctx_part[((size_t)sl * B + b) * CTX + c];
        x_dec[(size_t)b * RNN + ATT + c] = s;
    }

    const float* eb = e + (size_t)b * T;
    const float* wb = w + (size_t)b * T;
    const float e0 = eb[tid], e1 = eb[tid + 256];

    float m = fmaxf(e0, e1);
    #pragma unroll
    for (int o = 32; o; o >>= 1) m = fmaxf(m, __shfl_xor(m, o));
    if (lane == 0) red[wave] = m;
    __syncthreads();
    m = fmaxf(fmaxf(red[0], red[1]), fmaxf(red[2], red[3]));
    __syncthreads();

    const float x0 = expf(e0 - m), x1 = expf(e1 - m);
    float s = x0 + x1;
    #pragma unroll
    for (int o = 32; o; o >>= 1) s += __shfl_xor(s, o);
    if (lane == 0) red[wave] = s;
    __syncthreads();
    s = red[0] + red[1] + red[2] + red[3];
    __syncthreads();

    const float p0 = 0.5f * (wb[tid] + (tid > 0 ? wb[tid - 1] : 0.f));
    const float p1 = 0.5f * (wb[tid + 256] + wb[tid + 255]);
    const float m0 = (x0 / s) * p0;
    const float m1 = (x1 / s) * p1;
    float s2 = m0 + m1;
    #pragma unroll
    for (int o = 32; o; o >>= 1) s2 += __shfl_xor(s2, o);
    if (lane == 0) red[wave] = s2;
    __syncthreads();
    s2 = red[0] + red[1] + red[2] + red[3];
    const float inv = 1.f / (s2 + 1e-8f);
    w_new[(size_t)b * T + tid] = m0 * inv;
    w_new[(size_t)b * T + tid + 256] = m1 * inv;
}

// ---------------------------------------------------------------------------
// gi GEMM dispatch: grid dim3(36, 4); C = A @ W^T into gi buffer
// ---------------------------------------------------------------------------
__global__ __launch_bounds__(256) void gemm_gi_kernel(
        const float* __restrict__ A, const float* __restrict__ W,
        float* __restrict__ C) {
    __shared__ __align__(16) short AH[4096];
    __shared__ __align__(16) short AL[4096];
    __shared__ __align__(16) short WH[4096];
    __shared__ __align__(16) short WL[4096];
    gemm64_body(A, W, C, blockIdx.y * 64, blockIdx.x * 64, threadIdx.x, AH, AL, WH, WL);
}

// ---------------------------------------------------------------------------
// GRU epilogue: bias + gates + residual. grid: 768 blocks x 256 thr
// ---------------------------------------------------------------------------
__global__ void gru_res_kernel(const float* __restrict__ gi, const float* __restrict__ gh,
                               const float* __restrict__ x_in, const float* __restrict__ h_prev,
                               const float* __restrict__ bi, const float* __restrict__ bh,
                               float* __restrict__ out0, float* __restrict__ out1) {
    const int idx = blockIdx.x * 256 + threadIdx.x;
    const int b = idx / RNN, j = idx % RNN;
    const float* gib = gi + (size_t)b * G3;
    const float* ghb = gh + (size_t)b * G3;
    const float ir = gib[j] + bi[j];
    const float iz = gib[RNN + j] + bi[RNN + j];
    const float in_ = gib[2 * RNN + j] + bi[2 * RNN + j];
    const float hr = ghb[j] + bh[j];
    const float hz = ghb[RNN + j] + bh[RNN + j];
    const float hn = ghb[2 * RNN + j] + bh[2 * RNN + j];
    const float r = 1.f / (1.f + expf(-(ir + hr)));
    const float z = 1.f / (1.f + expf(-(iz + hz)));
    const float n = tanhf(in_ + r * hn);
    const float res = (1.f - z) * n + z * h_prev[idx] + x_in[idx];
    out0[idx] = res;
    if (out1) out1[idx] = res;
}

// ---------------------------------------------------------------------------
extern "C" void kernel_launch(void* const* d_in, const int* in_sizes, int n_in,
                              void* d_out, int out_size, void* d_ws, size_t ws_size,
                              hipStream_t stream) {
    const float* x       = (const float*)d_in[0];
    const float* w       = (const float*)d_in[1];
    const float* h_att   = (const float*)d_in[2];
    const float* h_dec0  = (const float*)d_in[3];
    const float* h_dec1  = (const float*)d_in[4];
    const float* memory  = (const float*)d_in[5];
    const float* pre_w1  = (const float*)d_in[6];
    const float* pre_b1  = (const float*)d_in[7];
    const float* pre_w2  = (const float*)d_in[8];
    const float* pre_b2  = (const float*)d_in[9];
    const float* att_wi  = (const float*)d_in[10];
    const float* att_wh  = (const float*)d_in[11];
    const float* att_bi  = (const float*)d_in[12];
    const float* att_bh  = (const float*)d_in[13];
    const float* q_w     = (const float*)d_in[14];
    const float* q_b     = (const float*)d_in[15];
    const float* dec0_wi = (const float*)d_in[16];
    const float* dec0_wh = (const float*)d_in[17];
    const float* dec0_bi = (const float*)d_in[18];
    const float* dec0_bh = (const float*)d_in[19];
    const float* dec1_wi = (const float*)d_in[20];
    const float* dec1_wh = (const float*)d_in[21];
    const float* dec1_bi = (const float*)d_in[22];
    const float* dec1_bh = (const float*)d_in[23];

    float* out = (float*)d_out;
    float* o_h1a = out;                    // h1        (256*768)
    float* o_wn  = out + 196608;           // w_new     (256*512)
    float* o_ha  = out + 327680;           // h_att_new (256*256)
    float* o_h0  = out + 393216;           // h0        (256*768)
    float* o_h1b = out + 589824;           // h1 again  (256*768)

    float* ws     = (float*)d_ws;
    float* q      = ws;                    // 131072
    float* x_dec  = ws + 131072;           // 196608
    float* gi     = ws + 327680;           // 589824
    float* gh0    = ws + 917504;           // 589824
    float* gh1    = ws + 1507328;          // 589824
    float* ctxp   = ws + 2097152;          // 1048576  (8 slices x B x 512)
    float* e      = ws + 3145728;          // 131072
    unsigned* rowcnt = (unsigned*)(ws + 3276800);  // 256
    short* sb     = (short*)(ws + 3277056);        // bf16 hi/lo fragment area
    short* p1h = sb;             short* p1l = sb + 20480;
    short* p2h = sb + 40960;     short* p2l = sb + 57344;
    short* wih = sb + 73728;     short* wil = sb + 172032;
    short* whh = sb + 270336;    short* whl = sb + 466944;
    short* qwh = sb + 663552;    short* qwl = sb + 794624;

    prep_kernel<<<514, 256, 0, stream>>>(pre_w1, pre_w2, att_wi, att_wh, q_w,
                                         p1h, p1l, p2h, p2l, wih, wil, whh, whl, qwh, qwl,
                                         h_dec0, dec0_wh, h_dec1, dec1_wh, gh0, gh1, rowcnt);
    front_mfma_kernel<<<16, 512, 0, stream>>>(x, pre_b1, pre_b2, h_att, att_bi, att_bh, q_b,
                                              p1h, p1l, p2h, p2l, wih, wil, whh, whl, qwh, qwl,
                                              o_ha, x_dec, q);
    mempass_mid_kernel<<<dim3(8, B), 256, 0, stream>>>(memory, w, q, e, ctxp, x_dec, o_wn, rowcnt);

    gemm_gi_kernel<<<dim3(36, 4), 256, 0, stream>>>(x_dec, dec0_wi, gi);
    gru_res_kernel<<<768, 256, 0, stream>>>(gi, gh0, x_dec, h_dec0, dec0_bi, dec0_bh, o_h0, nullptr);

    gemm_gi_kernel<<<dim3(36, 4), 256, 0, stream>>>(o_h0, dec1_wi, gi);
    gru_res_kernel<<<768, 256, 0, stream>>>(gi, gh1, o_h0, h_dec1, dec1_bi, dec1_bh, o_h1a, o_h1b);
}

// Round 10
// 186.824 us; speedup vs baseline: 3.1862x; 3.1862x over previous
//
#include <hip/hip_runtime.h>
#include <math.h>

// Sizes (fixed for this problem)
#define B    256
#define T    512
#define CTX  512
#define MEL  160
#define PRE  128
#define ATT  256
#define RNN  768
#define G3   2304   // 3*RNN

typedef __attribute__((ext_vector_type(8))) short short8;
typedef __attribute__((ext_vector_type(4))) float f32x4;

__device__ __forceinline__ unsigned short f2bf(float f) {
    unsigned u = __float_as_uint(f);
    unsigned r = (u + 0x7fffu + ((u >> 16) & 1u)) >> 16;
    return (unsigned short)r;
}
__device__ __forceinline__ float bf2f(unsigned short h) {
    return __uint_as_float((unsigned)h << 16);
}

__device__ __forceinline__ void conv8(const float* p, short8* hi8, short8* lo8) {
    const float4 v0 = *(const float4*)p;
    const float4 v1 = *(const float4*)(p + 4);
    const float av[8] = {v0.x, v0.y, v0.z, v0.w, v1.x, v1.y, v1.z, v1.w};
    short hi[8], lo[8];
    #pragma unroll
    for (int u = 0; u < 8; ++u) {
        const unsigned short h = f2bf(av[u]);
        hi[u] = (short)h;
        lo[u] = (short)f2bf(av[u] - bf2f(h));
    }
    *hi8 = *(const short8*)hi;
    *lo8 = *(const short8*)lo;
}

// ---------------------------------------------------------------------------
// 64x64 bf16-MFMA split-precision GEMM tile body (verified R5-R8).
// ---------------------------------------------------------------------------
__device__ __forceinline__ void gemm64_body(
        const float* __restrict__ A, const float* __restrict__ W,
        float* __restrict__ C, int m0, int n0, int tid,
        short* AH, short* AL, short* WH, short* WL) {
    const int lane = tid & 63;
    const int wave = tid >> 6;
    const int wm = wave >> 1, wn = wave & 1;

    f32x4 acc[2][2] = {{{0.f, 0.f, 0.f, 0.f}, {0.f, 0.f, 0.f, 0.f}},
                       {{0.f, 0.f, 0.f, 0.f}, {0.f, 0.f, 0.f, 0.f}}};

    for (int k0 = 0; k0 < RNN; k0 += 64) {
        #pragma unroll
        for (int si = 0; si < 2; ++si) {
            const int s = tid + si * 256;
            const int sub = s >> 6;
            const int ln = s & 63;
            const int row = (sub >> 1) * 16 + (ln & 15);
            const int kk = (sub & 1) * 32 + (ln >> 4) * 8;
            conv8(A + (size_t)(m0 + row) * RNN + k0 + kk,
                  (short8*)&AH[s * 8], (short8*)&AL[s * 8]);
            conv8(W + (size_t)(n0 + row) * RNN + k0 + kk,
                  (short8*)&WH[s * 8], (short8*)&WL[s * 8]);
        }
        __syncthreads();

        #pragma unroll
        for (int ks = 0; ks < 2; ++ks) {
            short8 ah[2], al[2], wh[2], wl[2];
            #pragma unroll
            for (int i = 0; i < 2; ++i) {
                const int asub = ((wm * 2 + i) * 2 + ks);
                ah[i] = *(const short8*)&AH[(asub * 64 + lane) * 8];
                al[i] = *(const short8*)&AL[(asub * 64 + lane) * 8];
                const int wsub = ((wn * 2 + i) * 2 + ks);
                wh[i] = *(const short8*)&WH[(wsub * 64 + lane) * 8];
                wl[i] = *(const short8*)&WL[(wsub * 64 + lane) * 8];
            }
            #pragma unroll
            for (int i = 0; i < 2; ++i)
                #pragma unroll
                for (int j = 0; j < 2; ++j) {
                    acc[i][j] = __builtin_amdgcn_mfma_f32_16x16x32_bf16(ah[i], wh[j], acc[i][j], 0, 0, 0);
                    acc[i][j] = __builtin_amdgcn_mfma_f32_16x16x32_bf16(al[i], wh[j], acc[i][j], 0, 0, 0);
                    acc[i][j] = __builtin_amdgcn_mfma_f32_16x16x32_bf16(ah[i], wl[j], acc[i][j], 0, 0, 0);
                }
        }
        __syncthreads();
    }

    const int rowq = lane >> 4, col = lane & 15;
    #pragma unroll
    for (int i = 0; i < 2; ++i)
        #pragma unroll
        for (int j = 0; j < 2; ++j) {
            const int rbase = m0 + wm * 32 + i * 16 + rowq * 4;
            const int cidx = n0 + wn * 32 + j * 16 + col;
            #pragma unroll
            for (int r = 0; r < 4; ++r)
                C[(size_t)(rbase + r) * G3 + cidx] = acc[i][j][r];
        }
}

// ---------------------------------------------------------------------------
// prep: blocks [0,226) wconv (fragment-order hi/lo);
//       blocks [226,370): gh0 = h_dec0 @ dec0_wh^T (input-only dependency);
//       blocks [370,514): gh1 = h_dec1 @ dec1_wh^T.
// No cross-block sync anywhere — plain dispatch parallelism.
// ---------------------------------------------------------------------------
__global__ __launch_bounds__(256) void prep_kernel(
        const float* __restrict__ pw1, const float* __restrict__ pw2,
        const float* __restrict__ wi, const float* __restrict__ wh,
        const float* __restrict__ qw,
        short* __restrict__ p1h, short* __restrict__ p1l,
        short* __restrict__ p2h, short* __restrict__ p2l,
        short* __restrict__ wih, short* __restrict__ wil,
        short* __restrict__ whh, short* __restrict__ whl,
        short* __restrict__ qwh, short* __restrict__ qwl,
        const float* __restrict__ h_dec0, const float* __restrict__ dec0_wh,
        const float* __restrict__ h_dec1, const float* __restrict__ dec1_wh,
        float* __restrict__ gh0, float* __restrict__ gh1) {
    __shared__ __align__(16) short AH[4096];
    __shared__ __align__(16) short AL[4096];
    __shared__ __align__(16) short WH[4096];
    __shared__ __align__(16) short WL[4096];
    const int blk = blockIdx.x;
    const int tid = threadIdx.x;

    if (blk < 226) {
        int s = blk * 256 + tid;
        const float* src; short *dh, *dl; int K, KS, slot;
        if (s < 2560)                  { src = pw1; dh = p1h; dl = p1l; K = MEL; KS = 5; slot = s; }
        else if ((s -= 2560) < 2048)   { src = pw2; dh = p2h; dl = p2l; K = PRE; KS = 4; slot = s; }
        else if ((s -= 2048) < 12288)  { src = wi;  dh = wih; dl = wil; K = PRE; KS = 4; slot = s; }
        else if ((s -= 12288) < 24576) { src = wh;  dh = whh; dl = whl; K = ATT; KS = 8; slot = s; }
        else if ((s -= 24576) < 16384) { src = qw;  dh = qwh; dl = qwl; K = ATT; KS = 8; slot = s; }
        else return;
        const int lane = slot & 63;
        const int ks = (slot >> 6) % KS;
        const int nt = (slot >> 6) / KS;
        const int n = nt * 16 + (lane & 15);
        const int k = ks * 32 + (lane >> 4) * 8;
        conv8(src + (size_t)n * K + k,
              (short8*)(dh + (size_t)slot * 8), (short8*)(dl + (size_t)slot * 8));
        return;
    }
    const int u = blk - 226;
    const float* A; const float* W; float* C;
    int r;
    if (u < 144) { A = h_dec0; W = dec0_wh; C = gh0; r = u; }
    else         { A = h_dec1; W = dec1_wh; C = gh1; r = u - 144; }
    gemm64_body(A, W, C, (r / 36) * 64, (r % 36) * 64, tid, AH, AL, WH, WL);
}

// ---------------------------------------------------------------------------
// front_mfma: PreNet -> attention GRU -> q projection (R7-verbatim)
// grid: 16 blocks x 512 threads
// ---------------------------------------------------------------------------
__global__ __launch_bounds__(512) void front_mfma_kernel(
        const float* __restrict__ x, const float* __restrict__ b1,
        const float* __restrict__ b2, const float* __restrict__ h_att,
        const float* __restrict__ bi, const float* __restrict__ bh,
        const float* __restrict__ qb,
        const short* __restrict__ p1h, const short* __restrict__ p1l,
        const short* __restrict__ p2h, const short* __restrict__ p2l,
        const short* __restrict__ wih, const short* __restrict__ wil,
        const short* __restrict__ whh, const short* __restrict__ whl,
        const short* __restrict__ qwh, const short* __restrict__ qwl,
        float* __restrict__ h_att_out, float* __restrict__ x_dec,
        float* __restrict__ q) {
    __shared__ __align__(16) short AH[8][64][8];
    __shared__ __align__(16) short AL[8][64][8];
    __shared__ __align__(16) float S[16][RNN];
    __shared__ __align__(16) float S2[16][RNN];
    __shared__ __align__(16) float hs[16][ATT];

    const int tid = threadIdx.x;
    const int wave = tid >> 6, lane = tid & 63;
    const int mb = blockIdx.x * 16;
    const int col = lane & 15, rowq = lane >> 4;

    for (int i = tid; i < 16 * ATT; i += 512)
        hs[i >> 8][i & 255] = h_att[(size_t)(mb + (i >> 8)) * ATT + (i & 255)];
    if (tid < 320) {
        const int sub = tid >> 6, ln = tid & 63;
        const int row = ln & 15, kk = sub * 32 + (ln >> 4) * 8;
        conv8(x + (size_t)(mb + row) * MEL + kk, (short8*)AH[sub][ln], (short8*)AL[sub][ln]);
    }
    __syncthreads();

    {   // prenet layer 1: K=160 (KS=5)
        const int nt = wave;
        f32x4 acc = {0.f, 0.f, 0.f, 0.f};
        #pragma unroll
        for (int ks = 0; ks < 5; ++ks) {
            const short8 a_h = *(const short8*)AH[ks][lane];
            const short8 a_l = *(const short8*)AL[ks][lane];
            const size_t fo = ((size_t)(nt * 5 + ks) * 64 + lane) * 8;
            const short8 b_h = *(const short8*)(p1h + fo);
            const short8 b_l = *(const short8*)(p1l + fo);
            acc = __builtin_amdgcn_mfma_f32_16x16x32_bf16(a_h, b_h, acc, 0, 0, 0);
            acc = __builtin_amdgcn_mfma_f32_16x16x32_bf16(a_l, b_h, acc, 0, 0, 0);
            acc = __builtin_amdgcn_mfma_f32_16x16x32_bf16(a_h, b_l, acc, 0, 0, 0);
        }
        const int j = nt * 16 + col;
        const float bb = b1[j];
        #pragma unroll
        for (int r = 0; r < 4; ++r)
            S[rowq * 4 + r][j] = fmaxf(acc[r] + bb, 0.f);
    }
    __syncthreads();
    if (tid < 256) {
        const int sub = tid >> 6, ln = tid & 63;
        const int row = ln & 15, kk = sub * 32 + (ln >> 4) * 8;
        conv8(&S[row][kk], (short8*)AH[sub][ln], (short8*)AL[sub][ln]);
    }
    __syncthreads();

    {   // prenet layer 2: K=128 (KS=4)
        const int nt = wave;
        f32x4 acc = {0.f, 0.f, 0.f, 0.f};
        #pragma unroll
        for (int ks = 0; ks < 4; ++ks) {
            const short8 a_h = *(const short8*)AH[ks][lane];
            const short8 a_l = *(const short8*)AL[ks][lane];
            const size_t fo = ((size_t)(nt * 4 + ks) * 64 + lane) * 8;
            const short8 b_h = *(const short8*)(p2h + fo);
            const short8 b_l = *(const short8*)(p2l + fo);
            acc = __builtin_amdgcn_mfma_f32_16x16x32_bf16(a_h, b_h, acc, 0, 0, 0);
            acc = __builtin_amdgcn_mfma_f32_16x16x32_bf16(a_l, b_h, acc, 0, 0, 0);
            acc = __builtin_amdgcn_mfma_f32_16x16x32_bf16(a_h, b_l, acc, 0, 0, 0);
        }
        const int j = wave * 16 + col;
        const float bb = b2[j];
        #pragma unroll
        for (int r = 0; r < 4; ++r)
            S[rowq * 4 + r][j] = fmaxf(acc[r] + bb, 0.f);
    }
    __syncthreads();
    if (tid < 256) {
        const int sub = tid >> 6, ln = tid & 63;
        const int row = ln & 15, kk = sub * 32 + (ln >> 4) * 8;
        conv8(&S[row][kk], (short8*)AH[sub][ln], (short8*)AL[sub][ln]);
    }
    __syncthreads();

    // gi = h_pre @ wi^T : 48 ntiles, K=128
    for (int t = 0; t < 6; ++t) {
        const int nt = wave * 6 + t;
        f32x4 acc = {0.f, 0.f, 0.f, 0.f};
        #pragma unroll
        for (int ks = 0; ks < 4; ++ks) {
            const short8 a_h = *(const short8*)AH[ks][lane];
            const short8 a_l = *(const short8*)AL[ks][lane];
            const size_t fo = ((size_t)(nt * 4 + ks) * 64 + lane) * 8;
            const short8 b_h = *(const short8*)(wih + fo);
            const short8 b_l = *(const short8*)(wil + fo);
            acc = __builtin_amdgcn_mfma_f32_16x16x32_bf16(a_h, b_h, acc, 0, 0, 0);
            acc = __builtin_amdgcn_mfma_f32_16x16x32_bf16(a_l, b_h, acc, 0, 0, 0);
            acc = __builtin_amdgcn_mfma_f32_16x16x32_bf16(a_h, b_l, acc, 0, 0, 0);
        }
        const int j = nt * 16 + col;
        #pragma unroll
        for (int r = 0; r < 4; ++r) S[rowq * 4 + r][j] = acc[r];
    }
    __syncthreads();
    {   // conv h_att (K=256)
        const int sub = tid >> 6, ln = tid & 63;
        const int row = ln & 15, kk = sub * 32 + (ln >> 4) * 8;
        conv8(&hs[row][kk], (short8*)AH[sub][ln], (short8*)AL[sub][ln]);
    }
    __syncthreads();

    // gh = h_att @ wh^T : K=256
    for (int t = 0; t < 6; ++t) {
        const int nt = wave * 6 + t;
        f32x4 acc = {0.f, 0.f, 0.f, 0.f};
        #pragma unroll
        for (int ks = 0; ks < 8; ++ks) {
            const short8 a_h = *(const short8*)AH[ks][lane];
            const short8 a_l = *(const short8*)AL[ks][lane];
            const size_t fo = ((size_t)(nt * 8 + ks) * 64 + lane) * 8;
            const short8 b_h = *(const short8*)(whh + fo);
            const short8 b_l = *(const short8*)(whl + fo);
            acc = __builtin_amdgcn_mfma_f32_16x16x32_bf16(a_h, b_h, acc, 0, 0, 0);
            acc = __builtin_amdgcn_mfma_f32_16x16x32_bf16(a_l, b_h, acc, 0, 0, 0);
            acc = __builtin_amdgcn_mfma_f32_16x16x32_bf16(a_h, b_l, acc, 0, 0, 0);
        }
        const int j = nt * 16 + col;
        #pragma unroll
        for (int r = 0; r < 4; ++r) S2[rowq * 4 + r][j] = acc[r];
    }
    __syncthreads();

    // gate math -> h_att_new
    for (int e = tid; e < 16 * ATT; e += 512) {
        const int b = e >> 8, j = e & 255;
        const float ir = S[b][j] + bi[j];
        const float iz = S[b][ATT + j] + bi[ATT + j];
        const float in_ = S[b][2 * ATT + j] + bi[2 * ATT + j];
        const float hr = S2[b][j] + bh[j];
        const float hz = S2[b][ATT + j] + bh[ATT + j];
        const float hn = S2[b][2 * ATT + j] + bh[2 * ATT + j];
        const float r = 1.f / (1.f + expf(-(ir + hr)));
        const float z = 1.f / (1.f + expf(-(iz + hz)));
        const float n = tanhf(in_ + r * hn);
        const float hnew = (1.f - z) * n + z * hs[b][j];
        h_att_out[(size_t)(mb + b) * ATT + j] = hnew;
        x_dec[(size_t)(mb + b) * RNN + j] = hnew;
        hs[b][j] = hnew;
    }
    __syncthreads();
    {   // conv h_att_new (K=256)
        const int sub = tid >> 6, ln = tid & 63;
        const int row = ln & 15, kk = sub * 32 + (ln >> 4) * 8;
        conv8(&hs[row][kk], (short8*)AH[sub][ln], (short8*)AL[sub][ln]);
    }
    __syncthreads();

    // q projection: K=256
    for (int t = 0; t < 4; ++t) {
        const int nt = wave * 4 + t;
        f32x4 acc = {0.f, 0.f, 0.f, 0.f};
        #pragma unroll
        for (int ks = 0; ks < 8; ++ks) {
            const short8 a_h = *(const short8*)AH[ks][lane];
            const short8 a_l = *(const short8*)AL[ks][lane];
            const size_t fo = ((size_t)(nt * 8 + ks) * 64 + lane) * 8;
            const short8 b_h = *(const short8*)(qwh + fo);
            const short8 b_l = *(const short8*)(qwl + fo);
            acc = __builtin_amdgcn_mfma_f32_16x16x32_bf16(a_h, b_h, acc, 0, 0, 0);
            acc = __builtin_amdgcn_mfma_f32_16x16x32_bf16(a_l, b_h, acc, 0, 0, 0);
            acc = __builtin_amdgcn_mfma_f32_16x16x32_bf16(a_h, b_l, acc, 0, 0, 0);
        }
        const int j = nt * 16 + col;
        const float bb = qb[j];
        #pragma unroll
        for (int r = 0; r < 4; ++r)
            q[(size_t)(mb + rowq * 4 + r) * CTX + j] = acc[r] + bb;
    }
}

// ---------------------------------------------------------------------------
// Fused memory pass (single read of memory): e scores + ctx partials
// grid: dim3(8, B) = 2048 blocks, 256 threads — R7-verbatim (measured best).
// NO cross-block sync, NO device-scope fences (R9 lesson: they collapse BW).
// ---------------------------------------------------------------------------
__global__ void mempass_kernel(const float* __restrict__ mem, const float* __restrict__ w,
                               const float* __restrict__ q, float* __restrict__ e,
                               float* __restrict__ ctx_part) {
    const int b = blockIdx.y, slice = blockIdx.x;
    const int tid = threadIdx.x;
    const int wave = tid >> 6, lane = tid & 63;
    __shared__ float qs[CTX];
    __shared__ float ctx_s[4][CTX];
    for (int i = tid; i < CTX; i += 256) qs[i] = q[(size_t)b * CTX + i];
    __syncthreads();

    const int c0 = lane * 4;
    const int c1 = 256 + lane * 4;
    const float q0 = qs[c0], q1 = qs[c0 + 1], q2 = qs[c0 + 2], q3 = qs[c0 + 3];
    const float q4 = qs[c1], q5 = qs[c1 + 1], q6 = qs[c1 + 2], q7 = qs[c1 + 3];

    const float* mb = mem + (size_t)b * T * CTX;
    float acc[8] = {0.f, 0.f, 0.f, 0.f, 0.f, 0.f, 0.f, 0.f};
    const float invs = 0.04419417382415922f;  // 1/sqrt(512)
    const int t0 = slice * 64 + wave * 16;

    #pragma unroll 4
    for (int i = 0; i < 16; ++i) {
        const int t = t0 + i;
        const float* row = mb + (size_t)t * CTX;
        const float4 m0 = *(const float4*)(row + c0);
        const float4 m1 = *(const float4*)(row + c1);
        const float wt = w[(size_t)b * T + t];
        float ep = m0.x * q0 + m0.y * q1 + m0.z * q2 + m0.w * q3
                 + m1.x * q4 + m1.y * q5 + m1.z * q6 + m1.w * q7;
        #pragma unroll
        for (int off = 32; off; off >>= 1) ep += __shfl_xor(ep, off);
        if (lane == 0) e[(size_t)b * T + t] = ep * invs;
        acc[0] += wt * m0.x; acc[1] += wt * m0.y; acc[2] += wt * m0.z; acc[3] += wt * m0.w;
        acc[4] += wt * m1.x; acc[5] += wt * m1.y; acc[6] += wt * m1.z; acc[7] += wt * m1.w;
    }
    ctx_s[wave][c0] = acc[0]; ctx_s[wave][c0 + 1] = acc[1]; ctx_s[wave][c0 + 2] = acc[2]; ctx_s[wave][c0 + 3] = acc[3];
    ctx_s[wave][c1] = acc[4]; ctx_s[wave][c1 + 1] = acc[5]; ctx_s[wave][c1 + 2] = acc[6]; ctx_s[wave][c1 + 3] = acc[7];
    __syncthreads();
    for (int c = tid; c < CTX; c += 256) {
        const float s = ctx_s[0][c] + ctx_s[1][c] + ctx_s[2][c] + ctx_s[3][c];
        ctx_part[((size_t)slice * B + b) * CTX + c] = s;
    }
}

// ---------------------------------------------------------------------------
// Fused mid: blocks 0..511 reduce ctx partials -> x_dec[:, 256:768]
//            blocks 512..767 softmax * Markov prior -> w_new  (R7-verbatim)
// ---------------------------------------------------------------------------
__global__ void mid_kernel(const float* __restrict__ part, float* __restrict__ x_dec,
                           const float* __restrict__ e, const float* __restrict__ w,
                           float* __restrict__ w_new) {
    const int tid = threadIdx.x;
    if (blockIdx.x < 512) {
        const int idx = blockIdx.x * 256 + tid;
        const int b = idx >> 9, c = idx & 511;
        float s = 0.f;
        #pragma unroll
        for (int sl = 0; sl < 8; ++sl) s += part[((size_t)sl * B + b) * CTX + c];
        x_dec[(size_t)b * RNN + ATT + c] = s;
        return;
    }
    const int b = blockIdx.x - 512;
    const int lane = tid & 63, wv = tid >> 6;
    __shared__ float red[4];
    const float* eb = e + (size_t)b * T;
    const float* wb = w + (size_t)b * T;
    const float e0 = eb[tid], e1 = eb[tid + 256];

    float m = fmaxf(e0, e1);
    #pragma unroll
    for (int o = 32; o; o >>= 1) m = fmaxf(m, __shfl_xor(m, o));
    if (lane == 0) red[wv] = m;
    __syncthreads();
    m = fmaxf(fmaxf(red[0], red[1]), fmaxf(red[2], red[3]));
    __syncthreads();

    const float x0 = expf(e0 - m), x1 = expf(e1 - m);
    float s = x0 + x1;
    #pragma unroll
    for (int o = 32; o; o >>= 1) s += __shfl_xor(s, o);
    if (lane == 0) red[wv] = s;
    __syncthreads();
    s = red[0] + red[1] + red[2] + red[3];
    __syncthreads();

    const float p0 = 0.5f * (wb[tid] + (tid > 0 ? wb[tid - 1] : 0.f));
    const float p1 = 0.5f * (wb[tid + 256] + wb[tid + 255]);
    const float m0 = (x0 / s) * p0;
    const float m1 = (x1 / s) * p1;
    float s2 = m0 + m1;
    #pragma unroll
    for (int o = 32; o; o >>= 1) s2 += __shfl_xor(s2, o);
    if (lane == 0) red[wv] = s2;
    __syncthreads();
    s2 = red[0] + red[1] + red[2] + red[3];
    const float inv = 1.f / (s2 + 1e-8f);
    w_new[(size_t)b * T + tid] = m0 * inv;
    w_new[(size_t)b * T + tid + 256] = m1 * inv;
}

// ---------------------------------------------------------------------------
// gi GEMM dispatch: grid dim3(36, 4); C = A @ W^T into gi buffer
// ---------------------------------------------------------------------------
__global__ __launch_bounds__(256) void gemm_gi_kernel(
        const float* __restrict__ A, const float* __restrict__ W,
        float* __restrict__ C) {
    __shared__ __align__(16) short AH[4096];
    __shared__ __align__(16) short AL[4096];
    __shared__ __align__(16) short WH[4096];
    __shared__ __align__(16) short WL[4096];
    gemm64_body(A, W, C, blockIdx.y * 64, blockIdx.x * 64, threadIdx.x, AH, AL, WH, WL);
}

// ---------------------------------------------------------------------------
// GRU epilogue: bias + gates + residual. grid: 768 blocks x 256 thr
// ---------------------------------------------------------------------------
__global__ void gru_res_kernel(const float* __restrict__ gi, const float* __restrict__ gh,
                               const float* __restrict__ x_in, const float* __restrict__ h_prev,
                               const float* __restrict__ bi, const float* __restrict__ bh,
                               float* __restrict__ out0, float* __restrict__ out1) {
    const int idx = blockIdx.x * 256 + threadIdx.x;
    const int b = idx / RNN, j = idx % RNN;
    const float* gib = gi + (size_t)b * G3;
    const float* ghb = gh + (size_t)b * G3;
    const float ir = gib[j] + bi[j];
    const float iz = gib[RNN + j] + bi[RNN + j];
    const float in_ = gib[2 * RNN + j] + bi[2 * RNN + j];
    const float hr = ghb[j] + bh[j];
    const float hz = ghb[RNN + j] + bh[RNN + j];
    const float hn = ghb[2 * RNN + j] + bh[2 * RNN + j];
    const float r = 1.f / (1.f + expf(-(ir + hr)));
    const float z = 1.f / (1.f + expf(-(iz + hz)));
    const float n = tanhf(in_ + r * hn);
    const float res = (1.f - z) * n + z * h_prev[idx] + x_in[idx];
    out0[idx] = res;
    if (out1) out1[idx] = res;
}

// ---------------------------------------------------------------------------
extern "C" void kernel_launch(void* const* d_in, const int* in_sizes, int n_in,
                              void* d_out, int out_size, void* d_ws, size_t ws_size,
                              hipStream_t stream) {
    const float* x       = (const float*)d_in[0];
    const float* w       = (const float*)d_in[1];
    const float* h_att   = (const float*)d_in[2];
    const float* h_dec0  = (const float*)d_in[3];
    const float* h_dec1  = (const float*)d_in[4];
    const float* memory  = (const float*)d_in[5];
    const float* pre_w1  = (const float*)d_in[6];
    const float* pre_b1  = (const float*)d_in[7];
    const float* pre_w2  = (const float*)d_in[8];
    const float* pre_b2  = (const float*)d_in[9];
    const float* att_wi  = (const float*)d_in[10];
    const float* att_wh  = (const float*)d_in[11];
    const float* att_bi  = (const float*)d_in[12];
    const float* att_bh  = (const float*)d_in[13];
    const float* q_w     = (const float*)d_in[14];
    const float* q_b     = (const float*)d_in[15];
    const float* dec0_wi = (const float*)d_in[16];
    const float* dec0_wh = (const float*)d_in[17];
    const float* dec0_bi = (const float*)d_in[18];
    const float* dec0_bh = (const float*)d_in[19];
    const float* dec1_wi = (const float*)d_in[20];
    const float* dec1_wh = (const float*)d_in[21];
    const float* dec1_bi = (const float*)d_in[22];
    const float* dec1_bh = (const float*)d_in[23];

    float* out = (float*)d_out;
    float* o_h1a = out;                    // h1        (256*768)
    float* o_wn  = out + 196608;           // w_new     (256*512)
    float* o_ha  = out + 327680;           // h_att_new (256*256)
    float* o_h0  = out + 393216;           // h0        (256*768)
    float* o_h1b = out + 589824;           // h1 again  (256*768)

    float* ws     = (float*)d_ws;
    float* q      = ws;                    // 131072
    float* x_dec  = ws + 131072;           // 196608
    float* gi     = ws + 327680;           // 589824
    float* gh0    = ws + 917504;           // 589824
    float* gh1    = ws + 1507328;          // 589824
    float* ctxp   = ws + 2097152;          // 1048576  (8 slices x B x 512)
    float* e      = ws + 3145728;          // 131072
    short* sb     = (short*)(ws + 3276800);// bf16 hi/lo fragment area
    short* p1h = sb;             short* p1l = sb + 20480;
    short* p2h = sb + 40960;     short* p2l = sb + 57344;
    short* wih = sb + 73728;     short* wil = sb + 172032;
    short* whh = sb + 270336;    short* whl = sb + 466944;
    short* qwh = sb + 663552;    short* qwl = sb + 794624;

    prep_kernel<<<514, 256, 0, stream>>>(pre_w1, pre_w2, att_wi, att_wh, q_w,
                                         p1h, p1l, p2h, p2l, wih, wil, whh, whl, qwh, qwl,
                                         h_dec0, dec0_wh, h_dec1, dec1_wh, gh0, gh1);
    front_mfma_kernel<<<16, 512, 0, stream>>>(x, pre_b1, pre_b2, h_att, att_bi, att_bh, q_b,
                                              p1h, p1l, p2h, p2l, wih, wil, whh, whl, qwh, qwl,
                                              o_ha, x_dec, q);
    mempass_kernel<<<dim3(8, B), 256, 0, stream>>>(memory, w, q, e, ctxp);
    mid_kernel<<<768, 256, 0, stream>>>(ctxp, x_dec, e, w, o_wn);

    gemm_gi_kernel<<<dim3(36, 4), 256, 0, stream>>>(x_dec, dec0_wi, gi);
    gru_res_kernel<<<768, 256, 0, stream>>>(gi, gh0, x_dec, h_dec0, dec0_bi, dec0_bh, o_h0, nullptr);

    gemm_gi_kernel<<<dim3(36, 4), 256, 0, stream>>>(o_h0, dec1_wi, gi);
    gru_res_kernel<<<768, 256, 0, stream>>>(gi, gh1, o_h0, h_dec1, dec1_bi, dec1_bh, o_h1a, o_h1b);
}

// Round 11
// 155.337 us; speedup vs baseline: 3.8320x; 1.2027x over previous
//
#include <hip/hip_runtime.h>
#include <math.h>

// Sizes (fixed for this problem)
#define B    256
#define T    512
#define CTX  512
#define MEL  160
#define PRE  128
#define ATT  256
#define RNN  768
#define G3   2304   // 3*RNN

typedef __attribute__((ext_vector_type(8))) short short8;
typedef __attribute__((ext_vector_type(4))) float f32x4;

__device__ __forceinline__ unsigned short f2bf(float f) {
    unsigned u = __float_as_uint(f);
    unsigned r = (u + 0x7fffu + ((u >> 16) & 1u)) >> 16;
    return (unsigned short)r;
}
__device__ __forceinline__ float bf2f(unsigned short h) {
    return __uint_as_float((unsigned)h << 16);
}

__device__ __forceinline__ void conv8(const float* p, short8* hi8, short8* lo8) {
    const float4 v0 = *(const float4*)p;
    const float4 v1 = *(const float4*)(p + 4);
    const float av[8] = {v0.x, v0.y, v0.z, v0.w, v1.x, v1.y, v1.z, v1.w};
    short hi[8], lo[8];
    #pragma unroll
    for (int u = 0; u < 8; ++u) {
        const unsigned short h = f2bf(av[u]);
        hi[u] = (short)h;
        lo[u] = (short)f2bf(av[u] - bf2f(h));
    }
    *hi8 = *(const short8*)hi;
    *lo8 = *(const short8*)lo;
}

// ---------------------------------------------------------------------------
// wconv: front weights fp32 -> bf16 hi/lo in MFMA FRAGMENT order (R7-verbatim)
// grid 226 x 256
// ---------------------------------------------------------------------------
__global__ void wconv_kernel(const float* __restrict__ pw1, const float* __restrict__ pw2,
                             const float* __restrict__ wi, const float* __restrict__ wh,
                             const float* __restrict__ qw,
                             short* __restrict__ p1h, short* __restrict__ p1l,
                             short* __restrict__ p2h, short* __restrict__ p2l,
                             short* __restrict__ wih, short* __restrict__ wil,
                             short* __restrict__ whh, short* __restrict__ whl,
                             short* __restrict__ qwh, short* __restrict__ qwl) {
    int s = blockIdx.x * 256 + threadIdx.x;
    const float* src; short *dh, *dl; int K, KS, slot;
    if (s < 2560)                       { src = pw1; dh = p1h; dl = p1l; K = MEL; KS = 5; slot = s; }
    else if ((s -= 2560) < 2048)        { src = pw2; dh = p2h; dl = p2l; K = PRE; KS = 4; slot = s; }
    else if ((s -= 2048) < 12288)       { src = wi;  dh = wih; dl = wil; K = PRE; KS = 4; slot = s; }
    else if ((s -= 12288) < 24576)      { src = wh;  dh = whh; dl = whl; K = ATT; KS = 8; slot = s; }
    else if ((s -= 24576) < 16384)      { src = qw;  dh = qwh; dl = qwl; K = ATT; KS = 8; slot = s; }
    else return;
    const int lane = slot & 63;
    const int ks = (slot >> 6) % KS;
    const int nt = (slot >> 6) / KS;
    const int n = nt * 16 + (lane & 15);
    const int k = ks * 32 + (lane >> 4) * 8;
    conv8(src + (size_t)n * K + k, (short8*)(dh + (size_t)slot * 8), (short8*)(dl + (size_t)slot * 8));
}

// ---------------------------------------------------------------------------
// front_mfma: PreNet -> attention GRU -> q projection (R7-verbatim)
// grid: 16 blocks x 512 threads
// ---------------------------------------------------------------------------
__global__ __launch_bounds__(512) void front_mfma_kernel(
        const float* __restrict__ x, const float* __restrict__ b1,
        const float* __restrict__ b2, const float* __restrict__ h_att,
        const float* __restrict__ bi, const float* __restrict__ bh,
        const float* __restrict__ qb,
        const short* __restrict__ p1h, const short* __restrict__ p1l,
        const short* __restrict__ p2h, const short* __restrict__ p2l,
        const short* __restrict__ wih, const short* __restrict__ wil,
        const short* __restrict__ whh, const short* __restrict__ whl,
        const short* __restrict__ qwh, const short* __restrict__ qwl,
        float* __restrict__ h_att_out, float* __restrict__ x_dec,
        float* __restrict__ q) {
    __shared__ __align__(16) short AH[8][64][8];
    __shared__ __align__(16) short AL[8][64][8];
    __shared__ __align__(16) float S[16][RNN];
    __shared__ __align__(16) float S2[16][RNN];
    __shared__ __align__(16) float hs[16][ATT];

    const int tid = threadIdx.x;
    const int wave = tid >> 6, lane = tid & 63;
    const int mb = blockIdx.x * 16;
    const int col = lane & 15, rowq = lane >> 4;

    for (int i = tid; i < 16 * ATT; i += 512)
        hs[i >> 8][i & 255] = h_att[(size_t)(mb + (i >> 8)) * ATT + (i & 255)];
    if (tid < 320) {
        const int sub = tid >> 6, ln = tid & 63;
        const int row = ln & 15, kk = sub * 32 + (ln >> 4) * 8;
        conv8(x + (size_t)(mb + row) * MEL + kk, (short8*)AH[sub][ln], (short8*)AL[sub][ln]);
    }
    __syncthreads();

    {   // prenet layer 1: K=160 (KS=5)
        const int nt = wave;
        f32x4 acc = {0.f, 0.f, 0.f, 0.f};
        #pragma unroll
        for (int ks = 0; ks < 5; ++ks) {
            const short8 a_h = *(const short8*)AH[ks][lane];
            const short8 a_l = *(const short8*)AL[ks][lane];
            const size_t fo = ((size_t)(nt * 5 + ks) * 64 + lane) * 8;
            const short8 b_h = *(const short8*)(p1h + fo);
            const short8 b_l = *(const short8*)(p1l + fo);
            acc = __builtin_amdgcn_mfma_f32_16x16x32_bf16(a_h, b_h, acc, 0, 0, 0);
            acc = __builtin_amdgcn_mfma_f32_16x16x32_bf16(a_l, b_h, acc, 0, 0, 0);
            acc = __builtin_amdgcn_mfma_f32_16x16x32_bf16(a_h, b_l, acc, 0, 0, 0);
        }
        const int j = nt * 16 + col;
        const float bb = b1[j];
        #pragma unroll
        for (int r = 0; r < 4; ++r)
            S[rowq * 4 + r][j] = fmaxf(acc[r] + bb, 0.f);
    }
    __syncthreads();
    if (tid < 256) {
        const int sub = tid >> 6, ln = tid & 63;
        const int row = ln & 15, kk = sub * 32 + (ln >> 4) * 8;
        conv8(&S[row][kk], (short8*)AH[sub][ln], (short8*)AL[sub][ln]);
    }
    __syncthreads();

    {   // prenet layer 2: K=128 (KS=4)
        const int nt = wave;
        f32x4 acc = {0.f, 0.f, 0.f, 0.f};
        #pragma unroll
        for (int ks = 0; ks < 4; ++ks) {
            const short8 a_h = *(const short8*)AH[ks][lane];
            const short8 a_l = *(const short8*)AL[ks][lane];
            const size_t fo = ((size_t)(nt * 4 + ks) * 64 + lane) * 8;
            const short8 b_h = *(const short8*)(p2h + fo);
            const short8 b_l = *(const short8*)(p2l + fo);
            acc = __builtin_amdgcn_mfma_f32_16x16x32_bf16(a_h, b_h, acc, 0, 0, 0);
            acc = __builtin_amdgcn_mfma_f32_16x16x32_bf16(a_l, b_h, acc, 0, 0, 0);
            acc = __builtin_amdgcn_mfma_f32_16x16x32_bf16(a_h, b_l, acc, 0, 0, 0);
        }
        const int j = wave * 16 + col;
        const float bb = b2[j];
        #pragma unroll
        for (int r = 0; r < 4; ++r)
            S[rowq * 4 + r][j] = fmaxf(acc[r] + bb, 0.f);
    }
    __syncthreads();
    if (tid < 256) {
        const int sub = tid >> 6, ln = tid & 63;
        const int row = ln & 15, kk = sub * 32 + (ln >> 4) * 8;
        conv8(&S[row][kk], (short8*)AH[sub][ln], (short8*)AL[sub][ln]);
    }
    __syncthreads();

    // gi = h_pre @ wi^T : 48 ntiles, K=128
    for (int t = 0; t < 6; ++t) {
        const int nt = wave * 6 + t;
        f32x4 acc = {0.f, 0.f, 0.f, 0.f};
        #pragma unroll
        for (int ks = 0; ks < 4; ++ks) {
            const short8 a_h = *(const short8*)AH[ks][lane];
            const short8 a_l = *(const short8*)AL[ks][lane];
            const size_t fo = ((size_t)(nt * 4 + ks) * 64 + lane) * 8;
            const short8 b_h = *(const short8*)(wih + fo);
            const short8 b_l = *(const short8*)(wil + fo);
            acc = __builtin_amdgcn_mfma_f32_16x16x32_bf16(a_h, b_h, acc, 0, 0, 0);
            acc = __builtin_amdgcn_mfma_f32_16x16x32_bf16(a_l, b_h, acc, 0, 0, 0);
            acc = __builtin_amdgcn_mfma_f32_16x16x32_bf16(a_h, b_l, acc, 0, 0, 0);
        }
        const int j = nt * 16 + col;
        #pragma unroll
        for (int r = 0; r < 4; ++r) S[rowq * 4 + r][j] = acc[r];
    }
    __syncthreads();
    {   // conv h_att (K=256)
        const int sub = tid >> 6, ln = tid & 63;
        const int row = ln & 15, kk = sub * 32 + (ln >> 4) * 8;
        conv8(&hs[row][kk], (short8*)AH[sub][ln], (short8*)AL[sub][ln]);
    }
    __syncthreads();

    // gh = h_att @ wh^T : K=256
    for (int t = 0; t < 6; ++t) {
        const int nt = wave * 6 + t;
        f32x4 acc = {0.f, 0.f, 0.f, 0.f};
        #pragma unroll
        for (int ks = 0; ks < 8; ++ks) {
            const short8 a_h = *(const short8*)AH[ks][lane];
            const short8 a_l = *(const short8*)AL[ks][lane];
            const size_t fo = ((size_t)(nt * 8 + ks) * 64 + lane) * 8;
            const short8 b_h = *(const short8*)(whh + fo);
            const short8 b_l = *(const short8*)(whl + fo);
            acc = __builtin_amdgcn_mfma_f32_16x16x32_bf16(a_h, b_h, acc, 0, 0, 0);
            acc = __builtin_amdgcn_mfma_f32_16x16x32_bf16(a_l, b_h, acc, 0, 0, 0);
            acc = __builtin_amdgcn_mfma_f32_16x16x32_bf16(a_h, b_l, acc, 0, 0, 0);
        }
        const int j = nt * 16 + col;
        #pragma unroll
        for (int r = 0; r < 4; ++r) S2[rowq * 4 + r][j] = acc[r];
    }
    __syncthreads();

    // gate math -> h_att_new
    for (int e = tid; e < 16 * ATT; e += 512) {
        const int b = e >> 8, j = e & 255;
        const float ir = S[b][j] + bi[j];
        const float iz = S[b][ATT + j] + bi[ATT + j];
        const float in_ = S[b][2 * ATT + j] + bi[2 * ATT + j];
        const float hr = S2[b][j] + bh[j];
        const float hz = S2[b][ATT + j] + bh[ATT + j];
        const float hn = S2[b][2 * ATT + j] + bh[2 * ATT + j];
        const float r = 1.f / (1.f + expf(-(ir + hr)));
        const float z = 1.f / (1.f + expf(-(iz + hz)));
        const float n = tanhf(in_ + r * hn);
        const float hnew = (1.f - z) * n + z * hs[b][j];
        h_att_out[(size_t)(mb + b) * ATT + j] = hnew;
        x_dec[(size_t)(mb + b) * RNN + j] = hnew;
        hs[b][j] = hnew;
    }
    __syncthreads();
    {   // conv h_att_new (K=256)
        const int sub = tid >> 6, ln = tid & 63;
        const int row = ln & 15, kk = sub * 32 + (ln >> 4) * 8;
        conv8(&hs[row][kk], (short8*)AH[sub][ln], (short8*)AL[sub][ln]);
    }
    __syncthreads();

    // q projection: K=256
    for (int t = 0; t < 4; ++t) {
        const int nt = wave * 4 + t;
        f32x4 acc = {0.f, 0.f, 0.f, 0.f};
        #pragma unroll
        for (int ks = 0; ks < 8; ++ks) {
            const short8 a_h = *(const short8*)AH[ks][lane];
            const short8 a_l = *(const short8*)AL[ks][lane];
            const size_t fo = ((size_t)(nt * 8 + ks) * 64 + lane) * 8;
            const short8 b_h = *(const short8*)(qwh + fo);
            const short8 b_l = *(const short8*)(qwl + fo);
            acc = __builtin_amdgcn_mfma_f32_16x16x32_bf16(a_h, b_h, acc, 0, 0, 0);
            acc = __builtin_amdgcn_mfma_f32_16x16x32_bf16(a_l, b_h, acc, 0, 0, 0);
            acc = __builtin_amdgcn_mfma_f32_16x16x32_bf16(a_h, b_l, acc, 0, 0, 0);
        }
        const int j = nt * 16 + col;
        const float bb = qb[j];
        #pragma unroll
        for (int r = 0; r < 4; ++r)
            q[(size_t)(mb + rowq * 4 + r) * CTX + j] = acc[r] + bb;
    }
}

// ---------------------------------------------------------------------------
// attn1024: one block per batch row, 1024 threads = 16 waves (16 waves/CU —
// twice R8's in-flight bytes, targeting full stream BW). Single read of
// memory[b]; e, ctx, softmax*prior all block-local. No fences (R9 lesson).
// ---------------------------------------------------------------------------
__global__ __launch_bounds__(1024) void attn_kernel(
        const float* __restrict__ mem, const float* __restrict__ w,
        const float* __restrict__ q, float* __restrict__ x_dec,
        float* __restrict__ w_new) {
    __shared__ float qs[CTX];
    __shared__ float ws_[T];
    __shared__ float e_s[T];
    __shared__ float ctx_s[16][CTX];
    __shared__ float red[16];

    const int b = blockIdx.x;
    const int tid = threadIdx.x;
    const int wave = tid >> 6, lane = tid & 63;

    if (tid < CTX) qs[tid] = q[(size_t)b * CTX + tid];
    else ws_[tid - CTX] = w[(size_t)b * T + tid - CTX];
    __syncthreads();

    const int c0 = lane * 4;
    const int c1 = 256 + lane * 4;
    const float q0 = qs[c0], q1 = qs[c0 + 1], q2 = qs[c0 + 2], q3 = qs[c0 + 3];
    const float q4 = qs[c1], q5 = qs[c1 + 1], q6 = qs[c1 + 2], q7 = qs[c1 + 3];

    const float* mb = mem + (size_t)b * T * CTX;
    float acc[8] = {0.f, 0.f, 0.f, 0.f, 0.f, 0.f, 0.f, 0.f};
    const float invs = 0.04419417382415922f;  // 1/sqrt(512)
    const int t0 = wave * 32;

    #pragma unroll 4
    for (int i = 0; i < 32; ++i) {
        const int t = t0 + i;
        const float* row = mb + (size_t)t * CTX;
        const float4 m0 = *(const float4*)(row + c0);
        const float4 m1 = *(const float4*)(row + c1);
        const float wt = ws_[t];
        float ep = m0.x * q0 + m0.y * q1 + m0.z * q2 + m0.w * q3
                 + m1.x * q4 + m1.y * q5 + m1.z * q6 + m1.w * q7;
        #pragma unroll
        for (int off = 32; off; off >>= 1) ep += __shfl_xor(ep, off);
        if (lane == 0) e_s[t] = ep * invs;
        acc[0] += wt * m0.x; acc[1] += wt * m0.y; acc[2] += wt * m0.z; acc[3] += wt * m0.w;
        acc[4] += wt * m1.x; acc[5] += wt * m1.y; acc[6] += wt * m1.z; acc[7] += wt * m1.w;
    }
    ctx_s[wave][c0] = acc[0]; ctx_s[wave][c0 + 1] = acc[1]; ctx_s[wave][c0 + 2] = acc[2]; ctx_s[wave][c0 + 3] = acc[3];
    ctx_s[wave][c1] = acc[4]; ctx_s[wave][c1 + 1] = acc[5]; ctx_s[wave][c1 + 2] = acc[6]; ctx_s[wave][c1 + 3] = acc[7];
    __syncthreads();

    // ctx reduce over 16 waves -> x_dec[b, 256+c]
    if (tid < CTX) {
        float s = 0.f;
        #pragma unroll
        for (int wv = 0; wv < 16; ++wv) s += ctx_s[wv][tid];
        x_dec[(size_t)b * RNN + ATT + tid] = s;
    }

    // softmax * Markov prior on first 8 waves (tid < 512); all threads hit
    // the __syncthreads(), only waves 0..7 write red[]/outputs.
    const bool act = (tid < T);
    float ev = act ? e_s[tid] : -1e30f;
    float m = ev;
    #pragma unroll
    for (int o = 32; o; o >>= 1) m = fmaxf(m, __shfl_xor(m, o));
    if (act && lane == 0) red[wave] = m;
    __syncthreads();
    m = red[0];
    #pragma unroll
    for (int wv = 1; wv < 8; ++wv) m = fmaxf(m, red[wv]);
    __syncthreads();

    const float x0 = act ? expf(ev - m) : 0.f;
    float s = x0;
    #pragma unroll
    for (int o = 32; o; o >>= 1) s += __shfl_xor(s, o);
    if (act && lane == 0) red[wave] = s;
    __syncthreads();
    s = red[0] + red[1] + red[2] + red[3] + red[4] + red[5] + red[6] + red[7];
    __syncthreads();

    const float p = act ? 0.5f * (ws_[tid] + (tid > 0 ? ws_[tid - 1] : 0.f)) : 0.f;
    const float m0v = (x0 / s) * p;
    float s2 = m0v;
    #pragma unroll
    for (int o = 32; o; o >>= 1) s2 += __shfl_xor(s2, o);
    if (act && lane == 0) red[wave] = s2;
    __syncthreads();
    s2 = red[0] + red[1] + red[2] + red[3] + red[4] + red[5] + red[6] + red[7];
    if (act) w_new[(size_t)b * T + tid] = m0v / (s2 + 1e-8f);
}

// ---------------------------------------------------------------------------
// bf16-MFMA split-precision GEMM: z=2 (gi,gh) — R7-verbatim
// ---------------------------------------------------------------------------
__global__ __launch_bounds__(256) void mfma_gemm_kernel(
        const float* __restrict__ Agi, const float* __restrict__ Agh,
        const float* __restrict__ Wgi, const float* __restrict__ Wgh,
        float* __restrict__ Cgi, float* __restrict__ Cgh) {
    const int mat = blockIdx.z;
    const float* __restrict__ A = mat ? Agh : Agi;
    const float* __restrict__ W = mat ? Wgh : Wgi;
    float* __restrict__ C = mat ? Cgh : Cgi;

    const int m0 = blockIdx.y * 64;
    const int n0 = blockIdx.x * 64;

    __shared__ __align__(16) short AH[4096];
    __shared__ __align__(16) short AL[4096];
    __shared__ __align__(16) short WH[4096];
    __shared__ __align__(16) short WL[4096];

    const int tid = threadIdx.x;
    const int lane = tid & 63;
    const int wave = tid >> 6;
    const int wm = wave >> 1, wn = wave & 1;

    f32x4 acc[2][2] = {{{0.f, 0.f, 0.f, 0.f}, {0.f, 0.f, 0.f, 0.f}},
                       {{0.f, 0.f, 0.f, 0.f}, {0.f, 0.f, 0.f, 0.f}}};

    for (int k0 = 0; k0 < RNN; k0 += 64) {
        #pragma unroll
        for (int si = 0; si < 2; ++si) {
            const int s = tid + si * 256;
            const int sub = s >> 6;
            const int ln = s & 63;
            const int row = (sub >> 1) * 16 + (ln & 15);
            const int kk = (sub & 1) * 32 + (ln >> 4) * 8;
            conv8(A + (size_t)(m0 + row) * RNN + k0 + kk,
                  (short8*)&AH[s * 8], (short8*)&AL[s * 8]);
            conv8(W + (size_t)(n0 + row) * RNN + k0 + kk,
                  (short8*)&WH[s * 8], (short8*)&WL[s * 8]);
        }
        __syncthreads();

        #pragma unroll
        for (int ks = 0; ks < 2; ++ks) {
            short8 ah[2], al[2], wh[2], wl[2];
            #pragma unroll
            for (int i = 0; i < 2; ++i) {
                const int asub = ((wm * 2 + i) * 2 + ks);
                ah[i] = *(const short8*)&AH[(asub * 64 + lane) * 8];
                al[i] = *(const short8*)&AL[(asub * 64 + lane) * 8];
                const int wsub = ((wn * 2 + i) * 2 + ks);
                wh[i] = *(const short8*)&WH[(wsub * 64 + lane) * 8];
                wl[i] = *(const short8*)&WL[(wsub * 64 + lane) * 8];
            }
            #pragma unroll
            for (int i = 0; i < 2; ++i)
                #pragma unroll
                for (int j = 0; j < 2; ++j) {
                    acc[i][j] = __builtin_amdgcn_mfma_f32_16x16x32_bf16(ah[i], wh[j], acc[i][j], 0, 0, 0);
                    acc[i][j] = __builtin_amdgcn_mfma_f32_16x16x32_bf16(al[i], wh[j], acc[i][j], 0, 0, 0);
                    acc[i][j] = __builtin_amdgcn_mfma_f32_16x16x32_bf16(ah[i], wl[j], acc[i][j], 0, 0, 0);
                }
        }
        __syncthreads();
    }

    const int rowq = lane >> 4, col = lane & 15;
    #pragma unroll
    for (int i = 0; i < 2; ++i)
        #pragma unroll
        for (int j = 0; j < 2; ++j) {
            const int rbase = m0 + wm * 32 + i * 16 + rowq * 4;
            const int cidx = n0 + wn * 32 + j * 16 + col;
            #pragma unroll
            for (int r = 0; r < 4; ++r)
                C[(size_t)(rbase + r) * G3 + cidx] = acc[i][j][r];
        }
}

// ---------------------------------------------------------------------------
// GRU epilogue: bias + gates + residual. grid: 768 blocks x 256 thr
// ---------------------------------------------------------------------------
__global__ void gru_res_kernel(const float* __restrict__ gi, const float* __restrict__ gh,
                               const float* __restrict__ x_in, const float* __restrict__ h_prev,
                               const float* __restrict__ bi, const float* __restrict__ bh,
                               float* __restrict__ out0, float* __restrict__ out1) {
    const int idx = blockIdx.x * 256 + threadIdx.x;
    const int b = idx / RNN, j = idx % RNN;
    const float* gib = gi + (size_t)b * G3;
    const float* ghb = gh + (size_t)b * G3;
    const float ir = gib[j] + bi[j];
    const float iz = gib[RNN + j] + bi[RNN + j];
    const float in_ = gib[2 * RNN + j] + bi[2 * RNN + j];
    const float hr = ghb[j] + bh[j];
    const float hz = ghb[RNN + j] + bh[RNN + j];
    const float hn = ghb[2 * RNN + j] + bh[2 * RNN + j];
    const float r = 1.f / (1.f + expf(-(ir + hr)));
    const float z = 1.f / (1.f + expf(-(iz + hz)));
    const float n = tanhf(in_ + r * hn);
    const float res = (1.f - z) * n + z * h_prev[idx] + x_in[idx];
    out0[idx] = res;
    if (out1) out1[idx] = res;
}

// ---------------------------------------------------------------------------
extern "C" void kernel_launch(void* const* d_in, const int* in_sizes, int n_in,
                              void* d_out, int out_size, void* d_ws, size_t ws_size,
                              hipStream_t stream) {
    const float* x       = (const float*)d_in[0];
    const float* w       = (const float*)d_in[1];
    const float* h_att   = (const float*)d_in[2];
    const float* h_dec0  = (const float*)d_in[3];
    const float* h_dec1  = (const float*)d_in[4];
    const float* memory  = (const float*)d_in[5];
    const float* pre_w1  = (const float*)d_in[6];
    const float* pre_b1  = (const float*)d_in[7];
    const float* pre_w2  = (const float*)d_in[8];
    const float* pre_b2  = (const float*)d_in[9];
    const float* att_wi  = (const float*)d_in[10];
    const float* att_wh  = (const float*)d_in[11];
    const float* att_bi  = (const float*)d_in[12];
    const float* att_bh  = (const float*)d_in[13];
    const float* q_w     = (const float*)d_in[14];
    const float* q_b     = (const float*)d_in[15];
    const float* dec0_wi = (const float*)d_in[16];
    const float* dec0_wh = (const float*)d_in[17];
    const float* dec0_bi = (const float*)d_in[18];
    const float* dec0_bh = (const float*)d_in[19];
    const float* dec1_wi = (const float*)d_in[20];
    const float* dec1_wh = (const float*)d_in[21];
    const float* dec1_bi = (const float*)d_in[22];
    const float* dec1_bh = (const float*)d_in[23];

    float* out = (float*)d_out;
    float* o_h1a = out;                    // h1        (256*768)
    float* o_wn  = out + 196608;           // w_new     (256*512)
    float* o_ha  = out + 327680;           // h_att_new (256*256)
    float* o_h0  = out + 393216;           // h0        (256*768)
    float* o_h1b = out + 589824;           // h1 again  (256*768)

    float* ws    = (float*)d_ws;
    float* q     = ws;                     // 131072
    float* x_dec = ws + 131072;            // 196608
    float* gi    = ws + 327680;            // 589824
    float* gh    = ws + 917504;            // 589824
    short* sb    = (short*)(ws + 1507328); // bf16 hi/lo fragment area
    short* p1h = sb;             short* p1l = sb + 20480;
    short* p2h = sb + 40960;     short* p2l = sb + 57344;
    short* wih = sb + 73728;     short* wil = sb + 172032;
    short* whh = sb + 270336;    short* whl = sb + 466944;
    short* qwh = sb + 663552;    short* qwl = sb + 794624;

    wconv_kernel<<<226, 256, 0, stream>>>(pre_w1, pre_w2, att_wi, att_wh, q_w,
                                          p1h, p1l, p2h, p2l, wih, wil, whh, whl, qwh, qwl);
    front_mfma_kernel<<<16, 512, 0, stream>>>(x, pre_b1, pre_b2, h_att, att_bi, att_bh, q_b,
                                              p1h, p1l, p2h, p2l, wih, wil, whh, whl, qwh, qwl,
                                              o_ha, x_dec, q);
    attn_kernel<<<B, 1024, 0, stream>>>(memory, w, q, x_dec, o_wn);

    mfma_gemm_kernel<<<dim3(G3 / 64, B / 64, 2), 256, 0, stream>>>(
        x_dec, h_dec0, dec0_wi, dec0_wh, gi, gh);
    gru_res_kernel<<<768, 256, 0, stream>>>(gi, gh, x_dec, h_dec0, dec0_bi, dec0_bh, o_h0, nullptr);

    mfma_gemm_kernel<<<dim3(G3 / 64, B / 64, 2), 256, 0, stream>>>(
        o_h0, h_dec1, dec1_wi, dec1_wh, gi, gh);
    gru_res_kernel<<<768, 256, 0, stream>>>(gi, gh, o_h0, h_dec1, dec1_bi, dec1_bh, o_h1a, o_h1b);
}